// Round 9
// baseline (438.512 us; speedup 1.0000x reference)
//
#include <hip/hip_runtime.h>

// Problem constants
#define B_     32
#define NOTES_ 78
#define T_     128
#define IN_    80
#define H_     128
#define NSEQ_  (B_*NOTES_)    // 2496
#define MBLK   16             // sequences per block (A-tile rows of 16x16x32 MFMA)
#define NBLK1  (NSEQ_/MBLK)   // 156 blocks
#define SEQ2_  (B_*T_)        // 4096 note-LSTM sequences
#define SHSTR  136            // sH row stride in shorts (272 B, 16B-aligned for b128)
#define SAXSTR 20             // accX col stride in floats (80 B: 16B-aligned, bank-spread)
#define NSTR   (SEQ2_*8)      // Gn note stride in floats (new [NOTES][SEQ2][8] layout)

typedef __attribute__((ext_vector_type(8))) short short8;   // 8 x bf16 (4 VGPRs)
typedef __attribute__((ext_vector_type(4))) float f32x4;

__device__ __forceinline__ unsigned short f2bf(float f) {
    unsigned u; __builtin_memcpy(&u, &f, 4);
    u += 0x7fffu + ((u >> 16) & 1u);          // RNE
    return (unsigned short)(u >> 16);
}
__device__ __forceinline__ short8 pack8(const float* p) {   // init-time only
    short8 r;
    #pragma unroll
    for (int k = 0; k < 8; ++k) r[k] = (short)f2bf(p[k]);
    return r;
}
__device__ __forceinline__ short8 pack8v(f32x4 a, f32x4 b) { // vector-load variant
    short8 r;
    #pragma unroll
    for (int k = 0; k < 4; ++k) { r[k] = (short)f2bf(a[k]); r[4+k] = (short)f2bf(b[k]); }
    return r;
}
__device__ __forceinline__ float rcpf(float x)  { return __builtin_amdgcn_rcpf(x); }
__device__ __forceinline__ float sigm(float x)  { return rcpf(1.f + __expf(-x)); }
__device__ __forceinline__ float tanhr(float x) { return 2.f * rcpf(1.f + __expf(-2.f*x)) - 1.f; }

// ---------------------------------------------------------------------------
// Fused time LSTM + note-gate pre-activations.  12 waves / 768 thr / block:
//   waves 0-7  = COMPUTE (r8 structure, unchanged): 16 h-cols x 4 gates each,
//                acc from LDS-staged accX, combined-rcp 4-cell update.
//   waves 8-11 = HELPER: gate u's Wih fragments, x loaded ONE STEP AHEAD
//                **directly as f32** (vectorized f32x4 + in-register bf16
//                pack -- xcvt kernel deleted; helpers have slack and are off
//                the h-critical path, so r3's compute-wave pressure problem
//                doesn't apply), accX staged to double-buffered LDS.
// ONE raw lgkmcnt-only barrier per step.  Gn layout CHANGED to
// [NOTES][SEQ2][8] so note_out's per-note loads coalesce.
// ---------------------------------------------------------------------------

// Note-gate tile for step TM1 (duty rotates over the 8 compute waves).
#define GN_TILE(TM1)                                                                   \
    if (wave == ((TM1) & 7)) {                                                         \
        short8 wnk[4];                                                                 \
        _Pragma("unroll")                                                              \
        for (int kt = 0; kt < 4; ++kt)                                                 \
            wnk[kt] = *(const short8*)(sWn + ((kt * 16 + m16) * 4 + quad) * 8);        \
        f32x4 an = (f32x4){0.f, 0.f, 0.f, 0.f};                                        \
        _Pragma("unroll")                                                              \
        for (int kt = 0; kt < 4; ++kt)                                                 \
            an = __builtin_amdgcn_mfma_f32_16x16x32_bf16(ah[kt], wnk[kt], an, 0, 0, 0);\
        if (m16 < 8) {                                                                 \
            _Pragma("unroll")                                                          \
            for (int r = 0; r < 4; ++r) {                                              \
                const int sq = seq0 + quad * 4 + r;                                    \
                const int bb = sq / NOTES_;                                            \
                const int nn = sq - bb * NOTES_;                                       \
                Gn[((unsigned)nn * SEQ2_ + (unsigned)bb * T_ + (unsigned)(TM1)) * 8u   \
                   + (unsigned)m16] = an[r] + bns;                                     \
            }                                                                          \
        }                                                                              \
    }

// Helper-side x load: f32, vectorized, packed to bf16 in-register.
#define LOADX(T)                                                                       \
    {                                                                                  \
        const float* p = xrf + (size_t)(T) * IN_;                                      \
        ax0 = pack8v(*(const f32x4*)(p + quad * 8),                                    \
                     *(const f32x4*)(p + quad * 8 + 4));                               \
        ax1 = pack8v(*(const f32x4*)(p + 32 + quad * 8),                               \
                     *(const f32x4*)(p + 32 + quad * 8 + 4));                          \
        if (quad < 2)                                                                  \
            ax2 = pack8v(*(const f32x4*)(p + 64 + quad * 8),                           \
                         *(const f32x4*)(p + 64 + quad * 8 + 4));                      \
    }

__global__ __launch_bounds__(768)
void time_lstm_kernel(
    const float* __restrict__ x,     // [NSEQ][T][IN] f32
    const float* __restrict__ Wih,   // [512][80]  f32
    const float* __restrict__ Whh,   // [512][128] f32
    const float* __restrict__ bih,   // [512] f32
    const float* __restrict__ bhh,   // [512] f32
    const float* __restrict__ Wn,    // [8][128] f32 (Wih_n)
    const float* __restrict__ bn1,   // [8] f32
    const float* __restrict__ bn2,   // [8] f32
    float* __restrict__ Gn)          // [NOTES][SEQ2][8] f32 (ws)
{
    __shared__ unsigned short sH[2][MBLK * SHSTR];   //  8704 B, double-buffered h
    __shared__ float sAx[2][512 * SAXSTR];           // 81920 B, double-buffered accX
    __shared__ unsigned short sWn[4 * 16 * 4 * 8];   //  4096 B, note-gate weights

    const int tid  = threadIdx.x;
    const int wave = tid >> 6, lane = tid & 63;
    const int m16  = lane & 15, quad = lane >> 4;
    const int seq0 = blockIdx.x * MBLK;

    for (int i = tid; i < 2 * MBLK * SHSTR; i += 768)
        ((unsigned short*)sH)[i] = 0;          // h(-1) = 0
    for (int i = tid; i < 4 * 16 * 4 * 8; i += 768) {
        const int e = i & 7, qq = (i >> 3) & 3, m = (i >> 5) & 15, kt = i >> 9;
        sWn[i] = (m < 8) ? f2bf(Wn[m * H_ + kt * 32 + qq * 8 + e]) : (unsigned short)0;
    }

    const short8 zero8 = (short8){0,0,0,0,0,0,0,0};
    const float bns = (m16 < 8) ? (bn1[m16] + bn2[m16]) : 0.f;

    if (wave < 8) {
        // =================== COMPUTE WAVE (r8 core, unchanged) =============
        const int j = wave * 16 + m16;         // this lane's h-column

        short8 hf[4][4];
        #pragma unroll
        for (int g = 0; g < 4; ++g) {
            const int n = g * H_ + j;
            #pragma unroll
            for (int kt = 0; kt < 4; ++kt)
                hf[g][kt] = pack8(Whh + n * H_ + kt * 32 + quad * 8);
        }
        float cst[4] = {0.f, 0.f, 0.f, 0.f};

        __syncthreads();                        // init fence

        for (int t = 0; t < T_; ++t) {
            const unsigned short* sHr = sH[t & 1];
            unsigned short*       sHw = sH[(t & 1) ^ 1];
            const float*          axr = sAx[t & 1];

            // h(t-1) A-fragments
            short8 ah[4];
            #pragma unroll
            for (int kt = 0; kt < 4; ++kt)
                ah[kt] = *(const short8*)(sHr + m16 * SHSTR + kt * 32 + quad * 8);

            // gate acc: init from staged accX (bias + x-part), 4-deep h chain
            f32x4 acc[4];
            #pragma unroll
            for (int g = 0; g < 4; ++g)
                acc[g] = *(const f32x4*)(axr + (g * H_ + j) * SAXSTR + quad * 4);
            __builtin_amdgcn_s_setprio(1);
            #pragma unroll
            for (int g = 0; g < 4; ++g) {
                #pragma unroll
                for (int kt = 0; kt < 4; ++kt)
                    acc[g] = __builtin_amdgcn_mfma_f32_16x16x32_bf16(ah[kt], hf[g][kt], acc[g], 0, 0, 0);
            }
            __builtin_amdgcn_s_setprio(0);

            // note-gate tile for step t-1 (duty 1/8, uses same ah)
            if (t > 0) GN_TILE(t - 1)

            // combined-rcp cell update, 4 cells
            float ei[4], ef[4], eg[4], eo[4];
            #pragma unroll
            for (int r = 0; r < 4; ++r) {
                ei[r] = __expf(-acc[0][r]);
                ef[r] = __expf(-acc[1][r]);
                eg[r] = __expf(-2.f * acc[2][r]);
                eo[r] = __expf(-acc[3][r]);
            }
            #pragma unroll
            for (int r = 0; r < 4; ++r) {
                const float di = 1.f + ei[r], df = 1.f + ef[r];
                const float dg = 1.f + eg[r], dd = 1.f + eo[r];
                const float s1 = di * df, s2 = dg * dd;
                const float R  = rcpf(s1 * s2);
                const float Rs2 = R * s2, Rs1 = R * s1;
                const float si = Rs2 * df;               // sigm(i)
                const float sf = Rs2 * di;               // sigm(f)
                const float so = Rs1 * dg;               // sigm(o)
                const float tg = 2.f * (Rs1 * dd) - 1.f; // tanh(g)
                const float cf = sf * cst[r] + si * tg;
                cst[r] = cf;
                const float h = so * tanhr(cf);
                sHw[(quad * 4 + r) * SHSTR + j] = f2bf(h);
            }

            // ONE barrier per step (lgkmcnt only; rule #18 sched fences)
            __builtin_amdgcn_sched_barrier(0);
            asm volatile("s_waitcnt lgkmcnt(0)" ::: "memory");
            __builtin_amdgcn_s_barrier();
            __builtin_amdgcn_sched_barrier(0);
        }

        // epilogue: note-gate tile for t = T-1 (h(127) sits in sH[0])
        {
            const unsigned short* sHr = sH[T_ & 1];
            short8 ah[4];
            #pragma unroll
            for (int kt = 0; kt < 4; ++kt)
                ah[kt] = *(const short8*)(sHr + m16 * SHSTR + kt * 32 + quad * 8);
            GN_TILE(T_ - 1)
        }
    } else {
        // =================== HELPER WAVE (x-side producer, f32 direct) =====
        const int u = wave - 8;                // owns gate u's 128 columns

        short8 wfh[8][3];
        float  bg8[8];
        #pragma unroll
        for (int nt = 0; nt < 8; ++nt) {
            const int n = u * H_ + nt * 16 + m16;   // gate-col in [128u,128u+128)
            #pragma unroll
            for (int kt = 0; kt < 3; ++kt) {
                const int k = kt * 32 + quad * 8;
                wfh[nt][kt] = (k < IN_) ? pack8(Wih + n * IN_ + k) : zero8;
            }
            bg8[nt] = bih[n] + bhh[n];
        }

        const float* xrf = x + (size_t)(seq0 + m16) * T_ * IN_;

        short8 ax0, ax1, ax2 = zero8;
        LOADX(0)                                // x(0)
        // prologue: accX(0) -> sAx[0]
        {
            float* wp = sAx[0];
            #pragma unroll
            for (int nt = 0; nt < 8; ++nt) {
                f32x4 a8 = (f32x4){bg8[nt], bg8[nt], bg8[nt], bg8[nt]};
                a8 = __builtin_amdgcn_mfma_f32_16x16x32_bf16(ax0, wfh[nt][0], a8, 0, 0, 0);
                a8 = __builtin_amdgcn_mfma_f32_16x16x32_bf16(ax1, wfh[nt][1], a8, 0, 0, 0);
                a8 = __builtin_amdgcn_mfma_f32_16x16x32_bf16(ax2, wfh[nt][2], a8, 0, 0, 0);
                *(f32x4*)(wp + (u * H_ + nt * 16 + m16) * SAXSTR + quad * 4) = a8;
            }
        }
        LOADX(1)                                // x(1)

        __syncthreads();                        // init fence

        for (int t = 0; t < T_; ++t) {
            // accX(t+1) = bias + x(t+1).Wih^T  -> sAx[(t+1)&1]
            if (t + 1 < T_) {
                float* wp = sAx[(t + 1) & 1];
                #pragma unroll
                for (int nt = 0; nt < 8; ++nt) {
                    f32x4 a8 = (f32x4){bg8[nt], bg8[nt], bg8[nt], bg8[nt]};
                    a8 = __builtin_amdgcn_mfma_f32_16x16x32_bf16(ax0, wfh[nt][0], a8, 0, 0, 0);
                    a8 = __builtin_amdgcn_mfma_f32_16x16x32_bf16(ax1, wfh[nt][1], a8, 0, 0, 0);
                    a8 = __builtin_amdgcn_mfma_f32_16x16x32_bf16(ax2, wfh[nt][2], a8, 0, 0, 0);
                    *(f32x4*)(wp + (u * H_ + nt * 16 + m16) * SAXSTR + quad * 4) = a8;
                }
            }
            // prefetch x(t+2): full-step window; never drained at barrier
            if (t + 2 < T_) LOADX(t + 2)

            __builtin_amdgcn_sched_barrier(0);
            asm volatile("s_waitcnt lgkmcnt(0)" ::: "memory");
            __builtin_amdgcn_s_barrier();
            __builtin_amdgcn_sched_barrier(0);
        }
    }
}

// ---------------------------------------------------------------------------
// Note-LSTM recurrence on precomputed pre-activations.
// Gn layout [NOTES][SEQ2][8]: at note n, consecutive lanes read consecutive
// 32B -> coalesced.  Grid 128 x 32-active-lane waves (128 CUs, 2x coverage of
// the old 64), 2-note-deep register prefetch (statically unrolled x2, rule
// #20), so per-note L2 latency (~600 cyc) is mostly covered.
// Gate order g: 0,1=i 2,3=f 4,5=g 6,7=o.
// ---------------------------------------------------------------------------
__global__ __launch_bounds__(64) void note_out_kernel(
    const float* __restrict__ Gn,    // [NOTES][SEQ2][8] f32
    const float* __restrict__ Whh,   // [8][2] f32
    float* __restrict__ out)         // [B][T][156] f32
{
    const int lane = threadIdx.x;
    if (lane >= 32) return;
    const int q = blockIdx.x * 32 + lane;      // grid 128 -> q in [0, 4096)

    float w0[8], w1[8];
    #pragma unroll
    for (int g = 0; g < 8; ++g) { w0[g] = Whh[g * 2]; w1[g] = Whh[g * 2 + 1]; }

    const float* gp = Gn + (size_t)q * 8;      // note stride = NSTR floats
    float* op = out + (size_t)q * (NOTES_ * 2);

    float h0 = 0.f, h1 = 0.f, c0 = 0.f, c1 = 0.f;

    // 2-deep prefetch pipeline, named registers (A = even note, B = odd note)
    f32x4 gaA = *(const f32x4*)(gp);
    f32x4 gbA = *(const f32x4*)(gp + 4);
    f32x4 gaB = *(const f32x4*)(gp + NSTR);
    f32x4 gbB = *(const f32x4*)(gp + NSTR + 4);

#define NOTE_BODY(GA, GB, N)                                                   \
    {                                                                          \
        const float i0 = GA[0] + w0[0] * h0 + w1[0] * h1;                      \
        const float i1 = GA[1] + w0[1] * h0 + w1[1] * h1;                      \
        const float f0 = GA[2] + w0[2] * h0 + w1[2] * h1;                      \
        const float f1 = GA[3] + w0[3] * h0 + w1[3] * h1;                      \
        const float g0 = GB[0] + w0[4] * h0 + w1[4] * h1;                      \
        const float g1 = GB[1] + w0[5] * h0 + w1[5] * h1;                      \
        const float o0 = GB[2] + w0[6] * h0 + w1[6] * h1;                      \
        const float o1 = GB[3] + w0[7] * h0 + w1[7] * h1;                      \
        c0 = sigm(f0) * c0 + sigm(i0) * tanhr(g0);                             \
        c1 = sigm(f1) * c1 + sigm(i1) * tanhr(g1);                             \
        h0 = sigm(o0) * tanhr(c0);                                             \
        h1 = sigm(o1) * tanhr(c1);                                             \
        op[(N) * 2 + 0] = h0;                                                  \
        op[(N) * 2 + 1] = h1;                                                  \
    }

    for (int n = 0; n < NOTES_; n += 2) {      // NOTES_ = 78, even
        NOTE_BODY(gaA, gbA, n)
        if (n + 2 < NOTES_) {
            gaA = *(const f32x4*)(gp + (size_t)(n + 2) * NSTR);
            gbA = *(const f32x4*)(gp + (size_t)(n + 2) * NSTR + 4);
        }
        NOTE_BODY(gaB, gbB, n + 1)
        if (n + 3 < NOTES_) {
            gaB = *(const f32x4*)(gp + (size_t)(n + 3) * NSTR);
            gbB = *(const f32x4*)(gp + (size_t)(n + 3) * NSTR + 4);
        }
    }
#undef NOTE_BODY
}

extern "C" void kernel_launch(void* const* d_in, const int* in_sizes, int n_in,
                              void* d_out, int out_size, void* d_ws, size_t ws_size,
                              hipStream_t stream) {
    const float* x     = (const float*)d_in[0];
    const float* Wih_t = (const float*)d_in[1];
    const float* Whh_t = (const float*)d_in[2];
    const float* bih_t = (const float*)d_in[3];
    const float* bhh_t = (const float*)d_in[4];
    const float* Wih_n = (const float*)d_in[5];
    const float* Whh_n = (const float*)d_in[6];
    const float* bih_n = (const float*)d_in[7];
    const float* bhh_n = (const float*)d_in[8];
    float* out = (float*)d_out;

    // Workspace: Gn only (10.2 MB), [NOTES][SEQ2][8] layout.
    float* Gn = (float*)d_ws;
    time_lstm_kernel<<<NBLK1, 768, 0, stream>>>(
        x, Wih_t, Whh_t, bih_t, bhh_t, Wih_n, bih_n, bhh_n, Gn);
    note_out_kernel<<<128, 64, 0, stream>>>(Gn, Whh_n, out);
}

// Round 10
// 384.408 us; speedup vs baseline: 1.1407x; 1.1407x over previous
//
#include <hip/hip_runtime.h>

// Problem constants
#define B_     32
#define NOTES_ 78
#define T_     128
#define IN_    80
#define H_     128
#define NSEQ_  (B_*NOTES_)    // 2496
#define MBLK   16             // sequences per block (A-tile rows of 16x16x32 MFMA)
#define NBLK1  (NSEQ_/MBLK)   // 156 blocks
#define SEQ2_  (B_*T_)        // 4096 note-LSTM sequences
#define SHSTR  136            // sH row stride in shorts (272 B, 16B-aligned for b128)
#define SAXSTR 20             // accX col stride in floats (80 B: 16B-aligned, bank-spread)

typedef __attribute__((ext_vector_type(8))) short short8;   // 8 x bf16 (4 VGPRs)
typedef __attribute__((ext_vector_type(4))) float f32x4;

__device__ __forceinline__ unsigned short f2bf(float f) {
    unsigned u; __builtin_memcpy(&u, &f, 4);
    u += 0x7fffu + ((u >> 16) & 1u);          // RNE
    return (unsigned short)(u >> 16);
}
__device__ __forceinline__ short8 pack8(const float* p) {   // init-time only
    short8 r;
    #pragma unroll
    for (int k = 0; k < 8; ++k) r[k] = (short)f2bf(p[k]);
    return r;
}
__device__ __forceinline__ short8 pack8v(f32x4 a, f32x4 b) {
    short8 r;
    #pragma unroll
    for (int k = 0; k < 4; ++k) { r[k] = (short)f2bf(a[k]); r[4+k] = (short)f2bf(b[k]); }
    return r;
}
__device__ __forceinline__ float rcpf(float x)  { return __builtin_amdgcn_rcpf(x); }
__device__ __forceinline__ float sigm(float x)  { return rcpf(1.f + __expf(-x)); }
__device__ __forceinline__ float tanhr(float x) { return 2.f * rcpf(1.f + __expf(-2.f*x)) - 1.f; }

// ---------------------------------------------------------------------------
// Fused time LSTM + note-gate pre-activations.  12 waves / 768 thr / block:
//   waves 0-7  = COMPUTE (r8 structure, byte-identical): 16 h-cols x 4 gates
//                each, acc from LDS-staged accX, combined-rcp 4-cell update.
//   waves 8-11 = HELPER: gate u's Wih fragments; x read DIRECTLY as f32 with
//                a true issue/consume split (T14): raw f32x4 loads of x(t+2)
//                into 6 named staging regs at step t (no pack at issue -> no
//                vmcnt stall), packed to bf16 only at consumption one full
//                step later (~3000cyc window >> 900cyc HBM latency).  This is
//                the fix for r9's regression, where pack-at-issue made the
//                "prefetch" a synchronous cold-HBM load every step.
// xcvt kernel DELETED (-27us dispatch, -153MB traffic).
// ONE raw lgkmcnt-only barrier per step; sH and accX double-buffered.
// Gn layout [B][T][NOTES][8] (r8's; note_out residual analysis r9 showed
// note_out ~30us, not worth the transposed-layout store scatter).
// ---------------------------------------------------------------------------

// Note-gate tile for step TM1 (duty rotates over the 8 compute waves).
#define GN_TILE(TM1)                                                                   \
    if (wave == ((TM1) & 7)) {                                                         \
        short8 wnk[4];                                                                 \
        _Pragma("unroll")                                                              \
        for (int kt = 0; kt < 4; ++kt)                                                 \
            wnk[kt] = *(const short8*)(sWn + ((kt * 16 + m16) * 4 + quad) * 8);        \
        f32x4 an = (f32x4){0.f, 0.f, 0.f, 0.f};                                        \
        _Pragma("unroll")                                                              \
        for (int kt = 0; kt < 4; ++kt)                                                 \
            an = __builtin_amdgcn_mfma_f32_16x16x32_bf16(ah[kt], wnk[kt], an, 0, 0, 0);\
        if (m16 < 8) {                                                                 \
            _Pragma("unroll")                                                          \
            for (int r = 0; r < 4; ++r) {                                              \
                const int sq = seq0 + quad * 4 + r;                                    \
                const int bb = sq / NOTES_;                                            \
                const int nn = sq - bb * NOTES_;                                       \
                Gn[((unsigned)bb * (T_ * NOTES_) + (unsigned)nn) * 8u + (unsigned)m16  \
                   + (unsigned)(TM1) * (NOTES_ * 8)] = an[r] + bns;                    \
            }                                                                          \
        }                                                                              \
    }

// Helper: ISSUE raw f32 loads of x(T) into staging regs (no pack, no use ->
// no vmcnt wait here); PACK consumes them a full step later.
#define ISSUEX(T)                                                                      \
    {                                                                                  \
        const float* p = xrf + (size_t)(T) * IN_;                                      \
        fx0a = *(const f32x4*)(p + quad * 8);                                          \
        fx0b = *(const f32x4*)(p + quad * 8 + 4);                                      \
        fx1a = *(const f32x4*)(p + 32 + quad * 8);                                     \
        fx1b = *(const f32x4*)(p + 32 + quad * 8 + 4);                                 \
        if (quad < 2) {                                                                \
            fx2a = *(const f32x4*)(p + 64 + quad * 8);                                 \
            fx2b = *(const f32x4*)(p + 64 + quad * 8 + 4);                             \
        }                                                                              \
    }
#define PACKX                                                                          \
    {                                                                                  \
        ax0 = pack8v(fx0a, fx0b);                                                      \
        ax1 = pack8v(fx1a, fx1b);                                                      \
        if (quad < 2) ax2 = pack8v(fx2a, fx2b);                                        \
    }

__global__ __launch_bounds__(768)
void time_lstm_kernel(
    const float* __restrict__ x,     // [NSEQ][T][IN] f32
    const float* __restrict__ Wih,   // [512][80]  f32
    const float* __restrict__ Whh,   // [512][128] f32
    const float* __restrict__ bih,   // [512] f32
    const float* __restrict__ bhh,   // [512] f32
    const float* __restrict__ Wn,    // [8][128] f32 (Wih_n)
    const float* __restrict__ bn1,   // [8] f32
    const float* __restrict__ bn2,   // [8] f32
    float* __restrict__ Gn)          // [B*T][NOTES][8] f32 (ws)
{
    __shared__ unsigned short sH[2][MBLK * SHSTR];   //  8704 B, double-buffered h
    __shared__ float sAx[2][512 * SAXSTR];           // 81920 B, double-buffered accX
    __shared__ unsigned short sWn[4 * 16 * 4 * 8];   //  4096 B, note-gate weights

    const int tid  = threadIdx.x;
    const int wave = tid >> 6, lane = tid & 63;
    const int m16  = lane & 15, quad = lane >> 4;
    const int seq0 = blockIdx.x * MBLK;

    for (int i = tid; i < 2 * MBLK * SHSTR; i += 768)
        ((unsigned short*)sH)[i] = 0;          // h(-1) = 0
    for (int i = tid; i < 4 * 16 * 4 * 8; i += 768) {
        const int e = i & 7, qq = (i >> 3) & 3, m = (i >> 5) & 15, kt = i >> 9;
        sWn[i] = (m < 8) ? f2bf(Wn[m * H_ + kt * 32 + qq * 8 + e]) : (unsigned short)0;
    }

    const short8 zero8 = (short8){0,0,0,0,0,0,0,0};
    const float bns = (m16 < 8) ? (bn1[m16] + bn2[m16]) : 0.f;

    if (wave < 8) {
        // =================== COMPUTE WAVE (r8 core, unchanged) =============
        const int j = wave * 16 + m16;         // this lane's h-column

        short8 hf[4][4];
        #pragma unroll
        for (int g = 0; g < 4; ++g) {
            const int n = g * H_ + j;
            #pragma unroll
            for (int kt = 0; kt < 4; ++kt)
                hf[g][kt] = pack8(Whh + n * H_ + kt * 32 + quad * 8);
        }
        float cst[4] = {0.f, 0.f, 0.f, 0.f};

        __syncthreads();                        // init fence

        for (int t = 0; t < T_; ++t) {
            const unsigned short* sHr = sH[t & 1];
            unsigned short*       sHw = sH[(t & 1) ^ 1];
            const float*          axr = sAx[t & 1];

            // h(t-1) A-fragments
            short8 ah[4];
            #pragma unroll
            for (int kt = 0; kt < 4; ++kt)
                ah[kt] = *(const short8*)(sHr + m16 * SHSTR + kt * 32 + quad * 8);

            // gate acc: init from staged accX (bias + x-part), 4-deep h chain
            f32x4 acc[4];
            #pragma unroll
            for (int g = 0; g < 4; ++g)
                acc[g] = *(const f32x4*)(axr + (g * H_ + j) * SAXSTR + quad * 4);
            __builtin_amdgcn_s_setprio(1);
            #pragma unroll
            for (int g = 0; g < 4; ++g) {
                #pragma unroll
                for (int kt = 0; kt < 4; ++kt)
                    acc[g] = __builtin_amdgcn_mfma_f32_16x16x32_bf16(ah[kt], hf[g][kt], acc[g], 0, 0, 0);
            }
            __builtin_amdgcn_s_setprio(0);

            // note-gate tile for step t-1 (duty 1/8, uses same ah)
            if (t > 0) GN_TILE(t - 1)

            // combined-rcp cell update, 4 cells
            float ei[4], ef[4], eg[4], eo[4];
            #pragma unroll
            for (int r = 0; r < 4; ++r) {
                ei[r] = __expf(-acc[0][r]);
                ef[r] = __expf(-acc[1][r]);
                eg[r] = __expf(-2.f * acc[2][r]);
                eo[r] = __expf(-acc[3][r]);
            }
            #pragma unroll
            for (int r = 0; r < 4; ++r) {
                const float di = 1.f + ei[r], df = 1.f + ef[r];
                const float dg = 1.f + eg[r], dd = 1.f + eo[r];
                const float s1 = di * df, s2 = dg * dd;
                const float R  = rcpf(s1 * s2);
                const float Rs2 = R * s2, Rs1 = R * s1;
                const float si = Rs2 * df;               // sigm(i)
                const float sf = Rs2 * di;               // sigm(f)
                const float so = Rs1 * dg;               // sigm(o)
                const float tg = 2.f * (Rs1 * dd) - 1.f; // tanh(g)
                const float cf = sf * cst[r] + si * tg;
                cst[r] = cf;
                const float h = so * tanhr(cf);
                sHw[(quad * 4 + r) * SHSTR + j] = f2bf(h);
            }

            // ONE barrier per step (lgkmcnt only; rule #18 sched fences)
            __builtin_amdgcn_sched_barrier(0);
            asm volatile("s_waitcnt lgkmcnt(0)" ::: "memory");
            __builtin_amdgcn_s_barrier();
            __builtin_amdgcn_sched_barrier(0);
        }

        // epilogue: note-gate tile for t = T-1 (h(127) sits in sH[0])
        {
            const unsigned short* sHr = sH[T_ & 1];
            short8 ah[4];
            #pragma unroll
            for (int kt = 0; kt < 4; ++kt)
                ah[kt] = *(const short8*)(sHr + m16 * SHSTR + kt * 32 + quad * 8);
            GN_TILE(T_ - 1)
        }
    } else {
        // ========== HELPER WAVE (x-side producer, f32 + issue/consume split)
        const int u = wave - 8;                // owns gate u's 128 columns

        short8 wfh[8][3];
        float  bg8[8];
        #pragma unroll
        for (int nt = 0; nt < 8; ++nt) {
            const int n = u * H_ + nt * 16 + m16;   // gate-col in [128u,128u+128)
            #pragma unroll
            for (int kt = 0; kt < 3; ++kt) {
                const int k = kt * 32 + quad * 8;
                wfh[nt][kt] = (k < IN_) ? pack8(Wih + n * IN_ + k) : zero8;
            }
            bg8[nt] = bih[n] + bhh[n];
        }

        const float* xrf = x + (size_t)(seq0 + m16) * T_ * IN_;

        f32x4 zf = (f32x4){0.f, 0.f, 0.f, 0.f};
        f32x4 fx0a = zf, fx0b = zf, fx1a = zf, fx1b = zf, fx2a = zf, fx2b = zf;
        short8 ax0, ax1, ax2 = zero8;

        ISSUEX(0)                               // issue x(0)
        PACKX                                   // consume (prologue: wait ok)
        {   // prologue: accX(0) -> sAx[0]
            float* wp = sAx[0];
            #pragma unroll
            for (int nt = 0; nt < 8; ++nt) {
                f32x4 a8 = (f32x4){bg8[nt], bg8[nt], bg8[nt], bg8[nt]};
                a8 = __builtin_amdgcn_mfma_f32_16x16x32_bf16(ax0, wfh[nt][0], a8, 0, 0, 0);
                a8 = __builtin_amdgcn_mfma_f32_16x16x32_bf16(ax1, wfh[nt][1], a8, 0, 0, 0);
                a8 = __builtin_amdgcn_mfma_f32_16x16x32_bf16(ax2, wfh[nt][2], a8, 0, 0, 0);
                *(f32x4*)(wp + (u * H_ + nt * 16 + m16) * SAXSTR + quad * 4) = a8;
            }
        }
        ISSUEX(1)                               // issue x(1); consumed at t=0

        __syncthreads();                        // init fence

        for (int t = 0; t < T_; ++t) {
            // accX(t+1) = bias + x(t+1).Wih^T  -> sAx[(t+1)&1]
            // (PACKX consumes loads issued LAST step: full-step latency window)
            if (t + 1 < T_) {
                PACKX
                float* wp = sAx[(t + 1) & 1];
                #pragma unroll
                for (int nt = 0; nt < 8; ++nt) {
                    f32x4 a8 = (f32x4){bg8[nt], bg8[nt], bg8[nt], bg8[nt]};
                    a8 = __builtin_amdgcn_mfma_f32_16x16x32_bf16(ax0, wfh[nt][0], a8, 0, 0, 0);
                    a8 = __builtin_amdgcn_mfma_f32_16x16x32_bf16(ax1, wfh[nt][1], a8, 0, 0, 0);
                    a8 = __builtin_amdgcn_mfma_f32_16x16x32_bf16(ax2, wfh[nt][2], a8, 0, 0, 0);
                    *(f32x4*)(wp + (u * H_ + nt * 16 + m16) * SAXSTR + quad * 4) = a8;
                }
            }
            // issue x(t+2) raw loads (no pack, no wait): in flight across
            // the barrier, consumed next step
            if (t + 2 < T_) ISSUEX(t + 2)

            __builtin_amdgcn_sched_barrier(0);
            asm volatile("s_waitcnt lgkmcnt(0)" ::: "memory");
            __builtin_amdgcn_s_barrier();
            __builtin_amdgcn_sched_barrier(0);
        }
    }
}

// ---------------------------------------------------------------------------
// Note-LSTM recurrence on precomputed pre-activations (r8 version).
// One thread per (b,t) sequence.  Gate order g: 0,1=i 2,3=f 4,5=g 6,7=o.
// ---------------------------------------------------------------------------
__global__ __launch_bounds__(64) void note_out_kernel(
    const float* __restrict__ Gn,    // [SEQ2_][NOTES][8] f32
    const float* __restrict__ Whh,   // [8][2] f32
    float* __restrict__ out)         // [B][T][156] f32
{
    const int q = blockIdx.x * 64 + threadIdx.x;
    if (q >= SEQ2_) return;

    float w0[8], w1[8];
    #pragma unroll
    for (int g = 0; g < 8; ++g) { w0[g] = Whh[g * 2]; w1[g] = Whh[g * 2 + 1]; }

    const float* gp = Gn + (size_t)q * (NOTES_ * 8);
    float* op = out + (size_t)q * (NOTES_ * 2);

    float h0 = 0.f, h1 = 0.f, c0 = 0.f, c1 = 0.f;
    f32x4 ga = *(const f32x4*)(gp);
    f32x4 gb = *(const f32x4*)(gp + 4);
    for (int n = 0; n < NOTES_; ++n) {
        f32x4 na, nb;
        if (n + 1 < NOTES_) {
            na = *(const f32x4*)(gp + (n + 1) * 8);
            nb = *(const f32x4*)(gp + (n + 1) * 8 + 4);
        }
        const float i0 = ga[0] + w0[0] * h0 + w1[0] * h1;
        const float i1 = ga[1] + w0[1] * h0 + w1[1] * h1;
        const float f0 = ga[2] + w0[2] * h0 + w1[2] * h1;
        const float f1 = ga[3] + w0[3] * h0 + w1[3] * h1;
        const float g0 = gb[0] + w0[4] * h0 + w1[4] * h1;
        const float g1 = gb[1] + w0[5] * h0 + w1[5] * h1;
        const float o0 = gb[2] + w0[6] * h0 + w1[6] * h1;
        const float o1 = gb[3] + w0[7] * h0 + w1[7] * h1;
        c0 = sigm(f0) * c0 + sigm(i0) * tanhr(g0);
        c1 = sigm(f1) * c1 + sigm(i1) * tanhr(g1);
        h0 = sigm(o0) * tanhr(c0);
        h1 = sigm(o1) * tanhr(c1);
        op[n * 2 + 0] = h0;
        op[n * 2 + 1] = h1;
        ga = na; gb = nb;
    }
}

extern "C" void kernel_launch(void* const* d_in, const int* in_sizes, int n_in,
                              void* d_out, int out_size, void* d_ws, size_t ws_size,
                              hipStream_t stream) {
    const float* x     = (const float*)d_in[0];
    const float* Wih_t = (const float*)d_in[1];
    const float* Whh_t = (const float*)d_in[2];
    const float* bih_t = (const float*)d_in[3];
    const float* bhh_t = (const float*)d_in[4];
    const float* Wih_n = (const float*)d_in[5];
    const float* Whh_n = (const float*)d_in[6];
    const float* bih_n = (const float*)d_in[7];
    const float* bhh_n = (const float*)d_in[8];
    float* out = (float*)d_out;

    // Workspace: Gn only (10.2 MB), [B][T][NOTES][8] layout.
    float* Gn = (float*)d_ws;
    time_lstm_kernel<<<NBLK1, 768, 0, stream>>>(
        x, Wih_t, Whh_t, bih_t, bhh_t, Wih_n, bih_n, bhh_n, Gn);
    note_out_kernel<<<SEQ2_ / 64, 64, 0, stream>>>(Gn, Whh_n, out);
}